// Round 4
// baseline (642.498 us; speedup 1.0000x reference)
//
#include <hip/hip_runtime.h>
#include <hip/hip_bf16.h>
#include <cstdint>
#include <cstddef>

// ---------- constants ----------
// B=8, N=4096, C=768, NUM_HEADS=8, HEAD_DIM=96, BN = B*N = 32768

#define GLOAD_LDS16(g, l) \
  __builtin_amdgcn_global_load_lds((const __attribute__((address_space(1))) void*)(g), \
                                   (__attribute__((address_space(3))) void*)(l), 16, 0, 0)

typedef __attribute__((ext_vector_type(8))) short bf16x8;
typedef __attribute__((ext_vector_type(4))) float f32x4;

__device__ __forceinline__ ushort f2bf(float f) {
  union { float f; uint32_t u; } v; v.f = f;
  uint32_t u = v.u;
  uint32_t r = u + 0x7fffu + ((u >> 16) & 1u);   // RTNE
  return (ushort)(r >> 16);
}

// ---------- K0: f32 -> bf16 convert (vectorized) ----------
__global__ __launch_bounds__(256) void k_conv(const float* __restrict__ src,
                                              ushort* __restrict__ dst, int n4) {
  int i = blockIdx.x * blockDim.x + threadIdx.x;
  int stride = gridDim.x * blockDim.x;
  for (; i < n4; i += stride) {
    float4 v = ((const float4*)src)[i];
    ushort4 o;
    o.x = f2bf(v.x); o.y = f2bf(v.y); o.z = f2bf(v.z); o.w = f2bf(v.w);
    ((ushort4*)dst)[i] = o;
  }
}

// ---------- softplus(scale_p) -> 1/scale ----------
__global__ void k_softplus(const float* __restrict__ p, float* __restrict__ sinv) {
  int i = threadIdx.x + blockIdx.x * 256;
  if (i < 768) {
    float x = p[i];
    float s = (x > 20.f) ? x : log1pf(expf(x));
    sinv[i] = 1.0f / s;
  }
}

// ---------- GEMM (B^T layout): C[M][Nc] = A[M][K=768] * Bt[Nc][K]  (+bias) ----------
// m97-style: 128x128 tile, BK=64, 4 waves (2x2), 16x16x32 bf16 MFMA, global_load_lds 16B
__global__ __launch_bounds__(256, 2) void gemm_bt(
    const ushort* __restrict__ A, const ushort* __restrict__ Bt,
    float* __restrict__ C, const float* __restrict__ bias, int Ncols) {
  constexpr int K = 768, BK = 64;
  __shared__ ushort lA[128 * BK];
  __shared__ ushort lB[128 * BK];
  const int tid  = threadIdx.x;
  const int lane = tid & 63;
  const int w    = tid >> 6;
  const int wr   = w >> 1, wc = w & 1;
  const int m0 = blockIdx.y * 128;
  const int n0 = blockIdx.x * 128;
  const int sr = lane >> 3;          // 0..7 (row within 8-row chunk)
  const int sc = (lane & 7) * 8;     // k-col within BK

  f32x4 acc[4][4] = {};

  for (int kt = 0; kt < K / BK; ++kt) {
    const int k0 = kt * BK;
    __syncthreads();
#pragma unroll
    for (int i = 0; i < 4; ++i) {
      const int ci = w * 4 + i;              // chunk 0..15 (8 rows each)
      const int r  = ci * 8 + sr;            // tile row 0..127
      GLOAD_LDS16(A  + (size_t)(m0 + r) * K + (k0 + sc), lA + ci * 512);
      GLOAD_LDS16(Bt + (size_t)(n0 + r) * K + (k0 + sc), lB + ci * 512);
    }
    __syncthreads();
#pragma unroll
    for (int kk = 0; kk < BK / 32; ++kk) {
      bf16x8 af[4], bfr[4];
#pragma unroll
      for (int m = 0; m < 4; ++m)
        af[m] = *(const bf16x8*)&lA[(wr * 64 + m * 16 + (lane & 15)) * BK + kk * 32 + (lane >> 4) * 8];
#pragma unroll
      for (int n = 0; n < 4; ++n)
        bfr[n] = *(const bf16x8*)&lB[(wc * 64 + n * 16 + (lane & 15)) * BK + kk * 32 + (lane >> 4) * 8];
#pragma unroll
      for (int m = 0; m < 4; ++m)
#pragma unroll
        for (int n = 0; n < 4; ++n)
          acc[m][n] = __builtin_amdgcn_mfma_f32_16x16x32_bf16(af[m], bfr[n], acc[m][n], 0, 0, 0);
    }
  }
  // epilogue: C/D layout col=lane&15, row=(lane>>4)*4+j  [m89-verified]
#pragma unroll
  for (int n = 0; n < 4; ++n) {
    const int col = n0 + wc * 64 + n * 16 + (lane & 15);
    const float bv = bias ? bias[col] : 0.0f;
#pragma unroll
    for (int m = 0; m < 4; ++m) {
      const int row0 = m0 + wr * 64 + m * 16 + (lane >> 4) * 4;
#pragma unroll
      for (int j = 0; j < 4; ++j)
        C[(size_t)(row0 + j) * Ncols + col] = acc[m][n][j] + bv;
    }
  }
}

// ---------- K2: A_raw[row] = (q_row . w_g) * sf ; per-batch sumsq ----------
__global__ __launch_bounds__(256) void k_arow(const float* __restrict__ qk,
                                              const float* __restrict__ wg,
                                              float* __restrict__ A_raw,
                                              float* __restrict__ bsumsq) {
  __shared__ float lwg[768];
  __shared__ float lsq[4];
  const int tid = threadIdx.x, lane = tid & 63, w = tid >> 6;
  for (int i = tid; i < 768; i += 256) lwg[i] = wg[i];
  __syncthreads();
  const float sf = 0.10206207261596575f;  // 96^-0.5
  float wsq = 0.f;
  for (int r8 = 0; r8 < 8; ++r8) {
    const int row = blockIdx.x * 32 + w * 8 + r8;
    const float* qr = qk + (size_t)row * 1536;
    float d = 0.f;
#pragma unroll
    for (int i = 0; i < 12; ++i) d += qr[lane + 64 * i] * lwg[lane + 64 * i];
#pragma unroll
    for (int m = 32; m; m >>= 1) d += __shfl_xor(d, m);
    d *= sf;
    if (lane == 0) { A_raw[row] = d; wsq += d * d; }
  }
  if (lane == 0) lsq[w] = wsq;
  __syncthreads();
  if (tid == 0) atomicAdd(&bsumsq[blockIdx.x >> 7], lsq[0] + lsq[1] + lsq[2] + lsq[3]);
}

// ---------- K3: rnorm[b] = 1/max(sqrt(sumsq),1e-12) ----------
__global__ void k_rnorm(const float* __restrict__ bsumsq, float* __restrict__ rnorm) {
  int t = threadIdx.x;
  if (t < 8) rnorm[t] = 1.0f / fmaxf(sqrtf(bsumsq[t]), 1e-12f);
}

// ---------- K4: accumulate G[b,c] = sum_n A_hat*q  and  ksum[b,c] = sum_n focus(k+pos) ----------
__global__ __launch_bounds__(256) void k_gks(const float* __restrict__ qk,
                                             const float* __restrict__ pos,
                                             const float* __restrict__ A_raw,
                                             const float* __restrict__ rnorm,
                                             const float* __restrict__ sinv,
                                             float* __restrict__ G,
                                             float* __restrict__ ksum) {
  __shared__ float red[8];
  __shared__ float lA[32];
  const int tid = threadIdx.x, lane = tid & 63, w = tid >> 6;
  const int b = blockIdx.x >> 7;
  if (tid < 32) lA[tid] = A_raw[blockIdx.x * 32 + tid] * rnorm[b];
  const int c0 = tid, c1 = tid + 256, c2 = tid + 512;
  const float sv0 = sinv[c0], sv1 = sinv[c1], sv2 = sinv[c2];
  float ga0 = 0, ga1 = 0, ga2 = 0, ka0 = 0, ka1 = 0, ka2 = 0;
  __syncthreads();
  for (int r = 0; r < 32; ++r) {
    const size_t row = (size_t)blockIdx.x * 32 + r;
    const float* qr = qk + row * 1536;
    const float* pr = pos + (row & 4095) * 768;
    float q0 = qr[c0], q1 = qr[c1], q2 = qr[c2];
    float t0 = (fmaxf(qr[768 + c0] + pr[c0], 0.f) + 1e-6f) * sv0;
    float t1 = (fmaxf(qr[768 + c1] + pr[c1], 0.f) + 1e-6f) * sv1;
    float t2 = (fmaxf(qr[768 + c2] + pr[c2], 0.f) + 1e-6f) * sv2;
    float u0 = t0 * t0 * t0, u1 = t1 * t1 * t1, u2 = t2 * t2 * t2;
    float s1 = t0 * t0 + t1 * t1 + t2 * t2;
    float s2 = u0 * u0 + u1 * u1 + u2 * u2;
#pragma unroll
    for (int m = 32; m; m >>= 1) { s1 += __shfl_xor(s1, m); s2 += __shfl_xor(s2, m); }
    if (lane == 0) { red[w * 2] = s1; red[w * 2 + 1] = s2; }
    __syncthreads();
    s1 = red[0] + red[2] + red[4] + red[6];
    s2 = red[1] + red[3] + red[5] + red[7];
    const float ratio = sqrtf(s1 / s2);     // ||t|| / ||t^3||
    const float a = lA[r];
    ka0 += u0 * ratio; ka1 += u1 * ratio; ka2 += u2 * ratio;
    ga0 += a * q0;     ga1 += a * q1;     ga2 += a * q2;
    __syncthreads();
  }
  atomicAdd(&G[b * 768 + c0], ga0); atomicAdd(&G[b * 768 + c1], ga1); atomicAdd(&G[b * 768 + c2], ga2);
  atomicAdd(&ksum[b * 768 + c0], ka0); atomicAdd(&ksum[b * 768 + c1], ka1); atomicAdd(&ksum[b * 768 + c2], ka2);
}

// ---------- K6: per row: focus(q), z per head, y = G*k*z  (bf16 out) ----------
__global__ __launch_bounds__(256) void k_y(const float* __restrict__ qk,
                                           const float* __restrict__ G,
                                           const float* __restrict__ ksum,
                                           const float* __restrict__ sinv,
                                           ushort* __restrict__ y) {
  __shared__ float red[8];
  __shared__ float zl[8];
  const int tid = threadIdx.x, lane = tid & 63, w = tid >> 6;
  const size_t row = blockIdx.x;
  const int b = blockIdx.x >> 12;
  const float* qr = qk + row * 1536;
  if (tid < 8) zl[tid] = 0.f;
  const int c0 = tid, c1 = tid + 256, c2 = tid + 512;
  const int h0 = c0 / 96, h1 = c1 / 96, h2 = c2 / 96;
  float t0 = (fmaxf(qr[c0], 0.f) + 1e-6f) * sinv[c0];
  float t1 = (fmaxf(qr[c1], 0.f) + 1e-6f) * sinv[c1];
  float t2 = (fmaxf(qr[c2], 0.f) + 1e-6f) * sinv[c2];
  float u0 = t0 * t0 * t0, u1 = t1 * t1 * t1, u2 = t2 * t2 * t2;
  float s1 = t0 * t0 + t1 * t1 + t2 * t2;
  float s2 = u0 * u0 + u1 * u1 + u2 * u2;
#pragma unroll
  for (int m = 32; m; m >>= 1) { s1 += __shfl_xor(s1, m); s2 += __shfl_xor(s2, m); }
  if (lane == 0) { red[w * 2] = s1; red[w * 2 + 1] = s2; }
  __syncthreads();
  s1 = red[0] + red[2] + red[4] + red[6];
  s2 = red[1] + red[3] + red[5] + red[7];
  const float ratio = sqrtf(s1 / s2);
  atomicAdd(&zl[h0], u0 * ratio * ksum[b * 768 + c0]);
  atomicAdd(&zl[h1], u1 * ratio * ksum[b * 768 + c1]);
  atomicAdd(&zl[h2], u2 * ratio * ksum[b * 768 + c2]);
  __syncthreads();
  const float inv_n = 1.0f / 4096.0f;
  float z0 = 1.0f / (zl[h0] * inv_n + 1e-6f);
  float z1 = 1.0f / (zl[h1] * inv_n + 1e-6f);
  float z2 = 1.0f / (zl[h2] * inv_n + 1e-6f);
  y[row * 768 + c0] = f2bf(G[b * 768 + c0] * qr[768 + c0] * z0);
  y[row * 768 + c1] = f2bf(G[b * 768 + c1] * qr[768 + c1] * z1);
  y[row * 768 + c2] = f2bf(G[b * 768 + c2] * qr[768 + c2] * z2);
}

// ---------- launcher ----------
extern "C" void kernel_launch(void* const* d_in, const int* in_sizes, int n_in,
                              void* d_out, int out_size, void* d_ws, size_t ws_size,
                              hipStream_t stream) {
  const float* x      = (const float*)d_in[0];
  const float* Wq     = (const float*)d_in[3];
  const float* Wkv    = (const float*)d_in[4];
  const float* Wproj  = (const float*)d_in[5];
  const float* bproj  = (const float*)d_in[6];
  const float* wg     = (const float*)d_in[7];
  const float* scalep = (const float*)d_in[8];
  const float* pos    = (const float*)d_in[9];

  char* ws = (char*)d_ws;
  float*  qk   = (float*)ws;                          // 32768*1536 f32 = 201326592 B
  ushort* xbf  = (ushort*)(ws + 201326592);           // 32768*768 bf16 = 50331648 B (reused as y)
  ushort* ybf  = xbf;
  ushort* wqk  = (ushort*)(ws + 251658240);           // 1536*768 bf16 = 2359296 B
  ushort* wpj  = (ushort*)(ws + 254017536);           // 768*768 bf16 = 1179648 B
  float*  sinv = (float*)(ws + 255197184);            // 768 f32
  float*  araw = (float*)(ws + 255200256);            // 32768 f32
  float*  acc  = (float*)(ws + 255331328);            // 8 + 6144 + 6144 + 8 f32
  float* bsumsq = acc;
  float* Gv     = acc + 8;
  float* ksum   = acc + 8 + 6144;
  float* rnorm  = acc + 8 + 12288;

  hipMemsetAsync(bsumsq, 0, (8 + 12288) * sizeof(float), stream);

  k_conv<<<4096, 256, 0, stream>>>(x, xbf, 25165824 / 4);
  k_conv<<<576, 256, 0, stream>>>(Wq, wqk, 589824 / 4);
  k_conv<<<576, 256, 0, stream>>>(Wkv, wqk + 589824, 589824 / 4);
  k_conv<<<576, 256, 0, stream>>>(Wproj, wpj, 589824 / 4);
  k_softplus<<<3, 256, 0, stream>>>(scalep, sinv);

  gemm_bt<<<dim3(12, 256), 256, 0, stream>>>(xbf, wqk, qk, nullptr, 1536);

  k_arow<<<1024, 256, 0, stream>>>(qk, wg, araw, bsumsq);
  k_rnorm<<<1, 64, 0, stream>>>(bsumsq, rnorm);
  k_gks<<<1024, 256, 0, stream>>>(qk, pos, araw, rnorm, sinv, Gv, ksum);
  k_y<<<32768, 256, 0, stream>>>(qk, Gv, ksum, sinv, ybf);

  gemm_bt<<<dim3(6, 256), 256, 0, stream>>>(ybf, wpj, (float*)d_out, bproj, 768);
}